// Round 9
// baseline (672.195 us; speedup 1.0000x reference)
//
#include <hip/hip_runtime.h>
#include <math.h>

#define BB 16
#define CC 128
#define TT 1024
#define KK 7
#define DK 64
#define NSPLIT 4
#define NBLK 512

typedef float f32x4 __attribute__((ext_vector_type(4)));
typedef short s16x8 __attribute__((ext_vector_type(8)));

__device__ inline short f2bf(float f) {
  union { float f; unsigned u; } v; v.f = f;
  unsigned r = (v.u + 0x7FFFu + ((v.u >> 16) & 1u)) >> 16;
  return (short)r;
}
__device__ inline float bf2f(short s) {
  union { unsigned u; float f; } v;
  v.u = ((unsigned)(unsigned short)s) << 16;
  return v.f;
}

// single-use grid barrier #k: barr[2k]=counter, barr[2k+1]=flag (zeroed before launch)
__device__ inline void grid_barrier(unsigned* barr, int k) {
  __syncthreads();
  if (threadIdx.x == 0) {
    __threadfence();  // release this block's writes to device scope
    unsigned prev = __hip_atomic_fetch_add(&barr[2 * k], 1u, __ATOMIC_ACQ_REL,
                                           __HIP_MEMORY_SCOPE_AGENT);
    if (prev == NBLK - 1) {
      __hip_atomic_store(&barr[2 * k + 1], 1u, __ATOMIC_RELEASE, __HIP_MEMORY_SCOPE_AGENT);
    } else {
      while (__hip_atomic_load(&barr[2 * k + 1], __ATOMIC_ACQUIRE,
                               __HIP_MEMORY_SCOPE_AGENT) == 0u) {
        __builtin_amdgcn_s_sleep(8);
      }
    }
    __threadfence();
  }
  __syncthreads();
}

// block-wide (256 threads) reduce of (s,ss) -> dst[0..1]
__device__ inline void block_partial_256(float s, float ss, float* dst) {
#pragma unroll
  for (int off = 32; off; off >>= 1) { s += __shfl_xor(s, off); ss += __shfl_xor(ss, off); }
  __shared__ float red[8];
  int w = threadIdx.x >> 6;
  if ((threadIdx.x & 63) == 0) { red[2 * w] = s; red[2 * w + 1] = ss; }
  __syncthreads();
  if (threadIdx.x == 0) {
    for (int i = 1; i < 4; ++i) { s += red[2 * i]; ss += red[2 * i + 1]; }
    dst[0] = s; dst[1] = ss;
  }
}

__device__ inline void ln_stats_from_parts(const float* part_batch, int n, float* sh) {
  if (threadIdx.x < 64) {
    float s = 0.f, ss = 0.f;
    for (int i = threadIdx.x; i < n; i += 64) { s += part_batch[2 * i]; ss += part_batch[2 * i + 1]; }
#pragma unroll
    for (int off = 32; off; off >>= 1) { s += __shfl_xor(s, off); ss += __shfl_xor(ss, off); }
    if (threadIdx.x == 0) {
      const float invN = 1.f / (float)(CC * TT);
      float mu = s * invN;
      sh[0] = mu;
      sh[1] = rsqrtf(ss * invN - mu * mu + 1e-5f);
    }
  }
  __syncthreads();
}

struct MegaP {
  const float *x, *mask, *dww, *dwb, *pww, *pwb;
  const float *n0g, *n0b, *nsg, *nsb, *neg, *neb;
  const float *Wq, *Wk, *Wv, *Wo, *fcw, *fcb;
  float* out;
  float *part0, *parts, *pml;
  short *ob, *sb, *qb, *kb, *vt, *pacc;
  short *pwwb, *wqkvb, *wo2b, *fcwb;
  unsigned* barr;
};

// ---- one dsconv tile: [LN-in] depthwise(fp32) -> MFMA pointwise + relu + [LN-res] residual ----
__device__ void dsconv_tile(const short* __restrict__ in,
                            const float* __restrict__ lng, const float* __restrict__ lnb,
                            const float* __restrict__ dww, const float* __restrict__ dwb,
                            const short* __restrict__ pwwb, const float* __restrict__ pwb,
                            short* __restrict__ outp, float* __restrict__ partdst,
                            bool LN_IN, bool LN_RES, int tile, int b, float mu, float rs,
                            float (*xs)[33], short (*Dt)[136]) {
  int t0 = tile * 16;
  for (int ch = threadIdx.x; ch < 512; ch += 256) {
    int c = ch >> 2, half = ch & 3;
    int ts = t0 - 8 + half * 8;
    float v[8];
    if (ts >= 0 && ts < TT) {
      s16x8 raw = *(const s16x8*)(in + ((size_t)b * CC + c) * TT + ts);
      if (LN_IN) {
        float4 g0 = *(const float4*)(lng + c * TT + ts);
        float4 g1 = *(const float4*)(lng + c * TT + ts + 4);
        float4 b0 = *(const float4*)(lnb + c * TT + ts);
        float4 b1 = *(const float4*)(lnb + c * TT + ts + 4);
        float gg[8] = {g0.x, g0.y, g0.z, g0.w, g1.x, g1.y, g1.z, g1.w};
        float bb[8] = {b0.x, b0.y, b0.z, b0.w, b1.x, b1.y, b1.z, b1.w};
#pragma unroll
        for (int j = 0; j < 8; ++j) v[j] = (bf2f(raw[j]) - mu) * rs * gg[j] + bb[j];
      } else {
#pragma unroll
        for (int j = 0; j < 8; ++j) v[j] = bf2f(raw[j]);
      }
    } else {
#pragma unroll
      for (int j = 0; j < 8; ++j) v[j] = 0.f;
    }
#pragma unroll
    for (int j = 0; j < 8; ++j) xs[c][half * 8 + j] = v[j];
  }
  __syncthreads();
  for (int i = threadIdx.x; i < 16 * CC; i += 256) {
    int t = i >> 7, c = i & 127;
    float a = dwb[c];
#pragma unroll
    for (int j = 0; j < KK; ++j) a += dww[c * KK + j] * xs[c][t + 5 + j];
    Dt[t][c] = f2bf(a);
  }
  __syncthreads();

  int w = threadIdx.x >> 6, lane = threadIdx.x & 63;
  int lo = lane & 15, hi = lane >> 4;
  f32x4 acc[2];
#pragma unroll
  for (int mt = 0; mt < 2; ++mt) { acc[mt][0] = 0.f; acc[mt][1] = 0.f; acc[mt][2] = 0.f; acc[mt][3] = 0.f; }
#pragma unroll
  for (int ks = 0; ks < 4; ++ks) {
    s16x8 b0 = *(const s16x8*)&Dt[lo][ks * 32 + hi * 8];
    s16x8 a0 = *(const s16x8*)&pwwb[(size_t)(w * 32 + lo) * CC + ks * 32 + hi * 8];
    s16x8 a1 = *(const s16x8*)&pwwb[(size_t)(w * 32 + 16 + lo) * CC + ks * 32 + hi * 8];
    acc[0] = __builtin_amdgcn_mfma_f32_16x16x32_bf16(a0, b0, acc[0], 0, 0, 0);
    acc[1] = __builtin_amdgcn_mfma_f32_16x16x32_bf16(a1, b0, acc[1], 0, 0, 0);
  }
  float s = 0.f, ss = 0.f;
#pragma unroll
  for (int mt = 0; mt < 2; ++mt)
#pragma unroll
    for (int r = 0; r < 4; ++r) {
      int row = w * 32 + mt * 16 + hi * 4 + r;
      int t = t0 + lo;
      float v = acc[mt][r] + pwb[row];
      v = v > 0.f ? v : 0.f;
      size_t idx = ((size_t)b * CC + row) * TT + t;
      float rv = bf2f(in[idx]);
      if (LN_RES) rv = (rv - mu) * rs * lng[row * TT + t] + lnb[row * TT + t];
      v += rv;
      outp[idx] = f2bf(v);
      s += v; ss += v * v;
    }
  block_partial_256(s, ss, partdst);
  __syncthreads();
}

__device__ void stage_dsconv(const MegaP& P, const short* in,
                             const float* lng, const float* lnb,
                             const float* part_in, int npart,
                             const float* dww, const float* dwb,
                             const short* pwwb, const float* pwb,
                             short* outp, float* part_out,
                             bool LN_IN, bool LN_RES,
                             float* s_stats, float (*xs)[33], short (*Dt)[136]) {
  int b = blockIdx.x >> 5, tg = blockIdx.x & 31;
  ln_stats_from_parts(part_in + (size_t)b * npart * 2, npart, s_stats);
  float mu = s_stats[0], rs = s_stats[1];
  __syncthreads();
  for (int tt = 0; tt < 2; ++tt) {
    int tile = tg * 2 + tt;
    dsconv_tile(in, lng, lnb, dww, dwb, pwwb, pwb, outp,
                part_out + ((size_t)b * 64 + tg * 2 + tt) * 2,
                LN_IN, LN_RES, tile, b, mu, rs, xs, Dt);
  }
}

__global__ __launch_bounds__(256, 2) void k_mega(MegaP P) {
  const int CT = CC * TT;
  __shared__ __align__(16) char smraw[21504];
  float* s_stats = (float*)smraw;
  float (*s_xs)[33] = (float(*)[33])(smraw + 16);
  short (*s_Dt)[136] = (short(*)[136])(smraw + 16 + 16896);
  short (*s_DtG)[136] = (short(*)[136])(smraw + 16);
  short (*s_ps)[16][72] = (short(*)[16][72])smraw;
  short (*s_Ht)[72] = (short(*)[72])smraw;

  // ======== S0: weight prep + pos-encoding add ========
  {
    int i = blockIdx.x * 256 + threadIdx.x;  // 512*256 = 131072 >= 114688
    if (i < 65536) { P.pwwb[i] = f2bf(P.pww[i]); }
    else if (i < 90112) {
      int j = i - 65536; int m = j >> 7, c = j & 127;
      int sel = m >> 6, d = m & 63;
      const float* sp2 = sel == 0 ? P.Wq : (sel == 1 ? P.Wk : P.Wv);
      P.wqkvb[j] = f2bf(sp2[c * DK + d]);
    } else if (i < 98304) {
      int j = i - 90112; int o = j >> 6, d = j & 63;
      P.wo2b[j] = f2bf(P.Wo[d * CC + o] + P.Wo[(d + 64) * CC + o]);
    } else if (i < 114688) {
      int j = i - 98304; P.fcwb[j] = f2bf(P.fcw[j]);
    }
    for (int rr = 0; rr < 4; ++rr) {
      int bc = blockIdx.x * 4 + rr;  // 0..2047
      int c = bc & (CC - 1);
      float ce = (float)(c & ~1);
      float freq = expf(-(ce / (float)CC) * 9.210340371976184f);
      float phase = (c & 1) ? 1.5707963267948966f : 0.0f;
      const float4* xr = (const float4*)(P.x + (size_t)bc * TT);
      short* orow = P.ob + (size_t)bc * TT;
      int t = threadIdx.x * 4;
      float4 xv = xr[threadIdx.x];
      float v0 = xv.x + sinf((float)t * freq + phase);
      float v1 = xv.y + sinf((float)(t + 1) * freq + phase);
      float v2 = xv.z + sinf((float)(t + 2) * freq + phase);
      float v3 = xv.w + sinf((float)(t + 3) * freq + phase);
      float s = v0 + v1 + v2 + v3;
      float ss = v0 * v0 + v1 * v1 + v2 * v2 + v3 * v3;
      short4 o4; o4.x = f2bf(v0); o4.y = f2bf(v1); o4.z = f2bf(v2); o4.w = f2bf(v3);
      *(short4*)(orow + t) = o4;
      block_partial_256(s, ss, P.part0 + (size_t)bc * 2);
      __syncthreads();
    }
  }
  grid_barrier(P.barr, 0);

  // ======== S1..S4: dsconv x4 (ping-pong ob<->sb) ========
  stage_dsconv(P, P.ob, P.n0g, P.n0b, P.part0, 128, P.dww, P.dwb, P.pwwb, P.pwb,
               P.sb, P.parts, false, true, s_stats, s_xs, s_Dt);
  grid_barrier(P.barr, 1);
  stage_dsconv(P, P.sb, P.nsg, P.nsb, P.parts, 64,
               P.dww + CC * KK, P.dwb + CC, P.pwwb + CC * CC, P.pwb + CC,
               P.ob, P.parts + 2048, true, false, s_stats, s_xs, s_Dt);
  grid_barrier(P.barr, 2);
  stage_dsconv(P, P.ob, P.nsg + CT, P.nsb + CT, P.parts + 2048, 64,
               P.dww + 2 * CC * KK, P.dwb + 2 * CC, P.pwwb + 2 * CC * CC, P.pwb + 2 * CC,
               P.sb, P.parts + 4096, true, false, s_stats, s_xs, s_Dt);
  grid_barrier(P.barr, 3);
  stage_dsconv(P, P.sb, P.nsg + 2 * CT, P.nsb + 2 * CT, P.parts + 4096, 64,
               P.dww + 3 * CC * KK, P.dwb + 3 * CC, P.pwwb + 3 * CC * CC, P.pwb + 3 * CC,
               P.ob, P.parts + 6144, true, false, s_stats, s_xs, s_Dt);
  grid_barrier(P.barr, 4);

  // ======== S5: qkv (LN_3 fused), M=192 stacked ========
  {
    int b = blockIdx.x >> 5, tg = blockIdx.x & 31;
    const float* lng = P.nsg + 3 * CT;
    const float* lnb = P.nsb + 3 * CT;
    ln_stats_from_parts(P.parts + 6144 + (size_t)b * 128, 64, s_stats);
    float mu = s_stats[0], rs = s_stats[1];
    __syncthreads();
    for (int tt = 0; tt < 2; ++tt) {
      int t0 = (tg * 2 + tt) * 16;
      {
        int i = threadIdx.x;
        int c = i >> 1, half = i & 1;
        int ts = t0 + half * 8;
        s16x8 raw = *(const s16x8*)(P.ob + ((size_t)b * CC + c) * TT + ts);
        float4 g0 = *(const float4*)(lng + c * TT + ts);
        float4 g1 = *(const float4*)(lng + c * TT + ts + 4);
        float4 b0 = *(const float4*)(lnb + c * TT + ts);
        float4 b1 = *(const float4*)(lnb + c * TT + ts + 4);
        float gg[8] = {g0.x, g0.y, g0.z, g0.w, g1.x, g1.y, g1.z, g1.w};
        float bb[8] = {b0.x, b0.y, b0.z, b0.w, b1.x, b1.y, b1.z, b1.w};
#pragma unroll
        for (int j = 0; j < 8; ++j)
          s_DtG[half * 8 + j][c] = f2bf((bf2f(raw[j]) - mu) * rs * gg[j] + bb[j]);
      }
      __syncthreads();
      int w = threadIdx.x >> 6, lane = threadIdx.x & 63;
      int lo = lane & 15, hi = lane >> 4;
      f32x4 acc[3];
#pragma unroll
      for (int mt = 0; mt < 3; ++mt) { acc[mt][0] = 0.f; acc[mt][1] = 0.f; acc[mt][2] = 0.f; acc[mt][3] = 0.f; }
#pragma unroll
      for (int ks = 0; ks < 4; ++ks) {
        s16x8 b0 = *(const s16x8*)&s_DtG[lo][ks * 32 + hi * 8];
#pragma unroll
        for (int mt = 0; mt < 3; ++mt) {
          s16x8 a = *(const s16x8*)&P.wqkvb[(size_t)(w * 48 + mt * 16 + lo) * CC + ks * 32 + hi * 8];
          acc[mt] = __builtin_amdgcn_mfma_f32_16x16x32_bf16(a, b0, acc[mt], 0, 0, 0);
        }
      }
#pragma unroll
      for (int mt = 0; mt < 3; ++mt) {
        int m0 = w * 48 + mt * 16 + hi * 4;
        int t = t0 + lo;
        short4 pk;
        pk.x = f2bf(acc[mt][0]); pk.y = f2bf(acc[mt][1]);
        pk.z = f2bf(acc[mt][2]); pk.w = f2bf(acc[mt][3]);
        if (m0 < 64) {
          *(short4*)(P.qb + ((size_t)b * TT + t) * DK + m0) = pk;
        } else if (m0 < 128) {
          *(short4*)(P.kb + ((size_t)b * TT + t) * DK + (m0 - 64)) = pk;
        } else {
          int d = m0 - 128;
          P.vt[((size_t)b * DK + d) * TT + t] = pk.x;
          P.vt[((size_t)b * DK + d + 1) * TT + t] = pk.y;
          P.vt[((size_t)b * DK + d + 2) * TT + t] = pk.z;
          P.vt[((size_t)b * DK + d + 3) * TT + t] = pk.w;
        }
      }
      __syncthreads();
    }
  }
  grid_barrier(P.barr, 5);

  // ======== S6: split-K flash attention, 2 units/block x 2 iterations ========
  for (int iter = 0; iter < 2; ++iter) {
    int gu = blockIdx.x * 2 + (threadIdx.x >> 7) + iter * 1024;  // 0..2047
    int sp = gu & (NSPLIT - 1);
    int qt = (gu >> 2) & 31;
    int b = gu >> 7;
    int w = threadIdx.x >> 6;
    int wq = w & 1;
    int lane = threadIdx.x & 63;
    int lo = lane & 15, hi = lane >> 4;

    const short* qp = P.qb + ((size_t)b * TT + qt * 32 + wq * 16 + lo) * DK + hi * 8;
    s16x8 aq0 = *(const s16x8*)qp;
    s16x8 aq1 = *(const s16x8*)(qp + 32);

    f32x4 acc[4];
    float m_i[4], l_i[4];
#pragma unroll
    for (int r = 0; r < 4; ++r) {
      m_i[r] = -3.0e38f; l_i[r] = 0.f;
#pragma unroll
      for (int nt = 0; nt < 4; ++nt) acc[nt][r] = 0.f;
    }
    const float scale = 0.125f;

    for (int kb2 = sp * (TT / 64 / NSPLIT); kb2 < (sp + 1) * (TT / 64 / NSPLIT); ++kb2) {
      f32x4 sc[4];
      float mv[4];
#pragma unroll
      for (int nt = 0; nt < 4; ++nt) {
        const short* kp = P.kb + ((size_t)b * TT + kb2 * 64 + nt * 16 + lo) * DK + hi * 8;
        s16x8 bk0 = *(const s16x8*)kp;
        s16x8 bk1 = *(const s16x8*)(kp + 32);
        f32x4 z; z[0] = 0.f; z[1] = 0.f; z[2] = 0.f; z[3] = 0.f;
        z = __builtin_amdgcn_mfma_f32_16x16x32_bf16(aq0, bk0, z, 0, 0, 0);
        z = __builtin_amdgcn_mfma_f32_16x16x32_bf16(aq1, bk1, z, 0, 0, 0);
        sc[nt] = z;
        mv[nt] = P.mask[(size_t)b * TT + kb2 * 64 + nt * 16 + lo];
      }
#pragma unroll
      for (int nt = 0; nt < 4; ++nt) {
        float addv = (1.f - mv[nt]) * -1e30f;
#pragma unroll
        for (int r = 0; r < 4; ++r) sc[nt][r] = sc[nt][r] * scale * mv[nt] + addv;
      }
      float alpha[4];
#pragma unroll
      for (int r = 0; r < 4; ++r) {
        float m0 = fmaxf(fmaxf(sc[0][r], sc[1][r]), fmaxf(sc[2][r], sc[3][r]));
#pragma unroll
        for (int off = 1; off < 16; off <<= 1) m0 = fmaxf(m0, __shfl_xor(m0, off));
        float mn = fmaxf(m_i[r], m0);
        alpha[r] = __expf(m_i[r] - mn);
        m_i[r] = mn;
      }
      float psum[4] = {0.f, 0.f, 0.f, 0.f};
#pragma unroll
      for (int nt = 0; nt < 4; ++nt)
#pragma unroll
        for (int r = 0; r < 4; ++r) {
          float p = __expf(sc[nt][r] - m_i[r]);
          psum[r] += p;
          s_ps[w][hi * 4 + r][nt * 16 + lo] = f2bf(p);
        }
#pragma unroll
      for (int r = 0; r < 4; ++r) {
        float sum = psum[r];
#pragma unroll
        for (int off = 1; off < 16; off <<= 1) sum += __shfl_xor(sum, off);
        l_i[r] = l_i[r] * alpha[r] + sum;
      }
#pragma unroll
      for (int nt = 0; nt < 4; ++nt)
#pragma unroll
        for (int r = 0; r < 4; ++r) acc[nt][r] *= alpha[r];

      s16x8 ap0 = *(const s16x8*)&s_ps[w][lo][hi * 8];
      s16x8 ap1 = *(const s16x8*)&s_ps[w][lo][32 + hi * 8];
#pragma unroll
      for (int nt = 0; nt < 4; ++nt) {
        const short* vp = P.vt + ((size_t)b * DK + nt * 16 + lo) * TT + kb2 * 64 + hi * 8;
        s16x8 bv0 = *(const s16x8*)vp;
        s16x8 bv1 = *(const s16x8*)(vp + 32);
        acc[nt] = __builtin_amdgcn_mfma_f32_16x16x32_bf16(ap0, bv0, acc[nt], 0, 0, 0);
        acc[nt] = __builtin_amdgcn_mfma_f32_16x16x32_bf16(ap1, bv1, acc[nt], 0, 0, 0);
      }
    }
#pragma unroll
    for (int r = 0; r < 4; ++r) {
      int row = qt * 32 + wq * 16 + hi * 4 + r;
      size_t pb = (((size_t)b * TT + row) * NSPLIT + sp) * DK;
#pragma unroll
      for (int nt = 0; nt < 4; ++nt) P.pacc[pb + nt * 16 + lo] = f2bf(acc[nt][r]);
      if (lo == 0) {
        size_t mb = (((size_t)b * TT + row) * NSPLIT + sp) * 2;
        P.pml[mb] = m_i[r];
        P.pml[mb + 1] = l_i[r];
      }
    }
  }
  grid_barrier(P.barr, 6);

  // ======== S7: combine split-K + heads@Wo2 + residual ========
  {
    int b = blockIdx.x >> 5, tg = blockIdx.x & 31;
    for (int tt = 0; tt < 2; ++tt) {
      int t0 = (tg * 2 + tt) * 16;
      if (threadIdx.x < 128) {
        int row = threadIdx.x >> 3, d8 = threadIdx.x & 7;
        size_t rb = (size_t)b * TT + t0 + row;
        float m[NSPLIT], l[NSPLIT];
#pragma unroll
        for (int s = 0; s < NSPLIT; ++s) {
          m[s] = P.pml[(rb * NSPLIT + s) * 2];
          l[s] = P.pml[(rb * NSPLIT + s) * 2 + 1];
        }
        float M = fmaxf(fmaxf(m[0], m[1]), fmaxf(m[2], m[3]));
        float wgt[NSPLIT], L = 0.f;
#pragma unroll
        for (int s = 0; s < NSPLIT; ++s) { wgt[s] = __expf(m[s] - M); L += wgt[s] * l[s]; }
        float inv = P.mask[rb] / L;
        float o[8];
#pragma unroll
        for (int j = 0; j < 8; ++j) o[j] = 0.f;
#pragma unroll
        for (int s = 0; s < NSPLIT; ++s) {
          s16x8 pv = *(const s16x8*)(P.pacc + (rb * NSPLIT + s) * DK + d8 * 8);
#pragma unroll
          for (int j = 0; j < 8; ++j) o[j] += wgt[s] * bf2f(pv[j]);
        }
        s16x8 hv;
#pragma unroll
        for (int j = 0; j < 8; ++j) hv[j] = f2bf(o[j] * inv);
        *(s16x8*)&s_Ht[row][d8 * 8] = hv;
      }
      __syncthreads();

      int w = threadIdx.x >> 6, lane = threadIdx.x & 63;
      int lo = lane & 15, hi = lane >> 4;
      f32x4 acc[2];
#pragma unroll
      for (int mt = 0; mt < 2; ++mt) { acc[mt][0] = 0.f; acc[mt][1] = 0.f; acc[mt][2] = 0.f; acc[mt][3] = 0.f; }
#pragma unroll
      for (int ks = 0; ks < 2; ++ks) {
        s16x8 b0 = *(const s16x8*)&s_Ht[lo][ks * 32 + hi * 8];
        s16x8 a0 = *(const s16x8*)&P.wo2b[(size_t)(w * 32 + lo) * DK + ks * 32 + hi * 8];
        s16x8 a1 = *(const s16x8*)&P.wo2b[(size_t)(w * 32 + 16 + lo) * DK + ks * 32 + hi * 8];
        acc[0] = __builtin_amdgcn_mfma_f32_16x16x32_bf16(a0, b0, acc[0], 0, 0, 0);
        acc[1] = __builtin_amdgcn_mfma_f32_16x16x32_bf16(a1, b0, acc[1], 0, 0, 0);
      }
      float s = 0.f, ss = 0.f;
#pragma unroll
      for (int mt = 0; mt < 2; ++mt)
#pragma unroll
        for (int r = 0; r < 4; ++r) {
          int row = w * 32 + mt * 16 + hi * 4 + r;
          int t = t0 + lo;
          size_t idx = ((size_t)b * CC + row) * TT + t;
          float v = acc[mt][r] + bf2f(P.ob[idx]);
          P.sb[idx] = f2bf(v);
          s += v; ss += v * v;
        }
      block_partial_256(s, ss, P.parts + 8192 + ((size_t)b * 64 + tg * 2 + tt) * 2);
      __syncthreads();
    }
  }
  grid_barrier(P.barr, 7);

  // ======== S8: FC (LN_e fused) + relu + residual -> d_out fp32 ========
  {
    int b = blockIdx.x >> 5, tg = blockIdx.x & 31;
    ln_stats_from_parts(P.parts + 8192 + (size_t)b * 128, 64, s_stats);
    float mu = s_stats[0], rs = s_stats[1];
    __syncthreads();
    for (int tt = 0; tt < 2; ++tt) {
      int t0 = (tg * 2 + tt) * 16;
      {
        int i = threadIdx.x;
        int c = i >> 1, half = i & 1;
        int ts = t0 + half * 8;
        s16x8 raw = *(const s16x8*)(P.sb + ((size_t)b * CC + c) * TT + ts);
        float4 g0 = *(const float4*)(P.neg + c * TT + ts);
        float4 g1 = *(const float4*)(P.neg + c * TT + ts + 4);
        float4 b0 = *(const float4*)(P.neb + c * TT + ts);
        float4 b1 = *(const float4*)(P.neb + c * TT + ts + 4);
        float gg[8] = {g0.x, g0.y, g0.z, g0.w, g1.x, g1.y, g1.z, g1.w};
        float bb[8] = {b0.x, b0.y, b0.z, b0.w, b1.x, b1.y, b1.z, b1.w};
#pragma unroll
        for (int j = 0; j < 8; ++j)
          s_DtG[half * 8 + j][c] = f2bf((bf2f(raw[j]) - mu) * rs * gg[j] + bb[j]);
      }
      __syncthreads();

      int w = threadIdx.x >> 6, lane = threadIdx.x & 63;
      int lo = lane & 15, hi = lane >> 4;
      f32x4 acc[2];
#pragma unroll
      for (int mt = 0; mt < 2; ++mt) { acc[mt][0] = 0.f; acc[mt][1] = 0.f; acc[mt][2] = 0.f; acc[mt][3] = 0.f; }
#pragma unroll
      for (int ks = 0; ks < 4; ++ks) {
        s16x8 b0 = *(const s16x8*)&s_DtG[lo][ks * 32 + hi * 8];
        s16x8 a0 = *(const s16x8*)&P.fcwb[(size_t)(w * 32 + lo) * CC + ks * 32 + hi * 8];
        s16x8 a1 = *(const s16x8*)&P.fcwb[(size_t)(w * 32 + 16 + lo) * CC + ks * 32 + hi * 8];
        acc[0] = __builtin_amdgcn_mfma_f32_16x16x32_bf16(a0, b0, acc[0], 0, 0, 0);
        acc[1] = __builtin_amdgcn_mfma_f32_16x16x32_bf16(a1, b0, acc[1], 0, 0, 0);
      }
#pragma unroll
      for (int mt = 0; mt < 2; ++mt)
#pragma unroll
        for (int r = 0; r < 4; ++r) {
          int row = w * 32 + mt * 16 + hi * 4 + r;
          int t = t0 + lo;
          size_t idx = ((size_t)b * CC + row) * TT + t;
          float v = acc[mt][r] + P.fcb[row];
          v = v > 0.f ? v : 0.f;
          P.out[idx] = v + bf2f(P.sb[idx]);
        }
      __syncthreads();
    }
  }
}

extern "C" void kernel_launch(void* const* d_in, const int* in_sizes, int n_in,
                              void* d_out, int out_size, void* d_ws, size_t ws_size,
                              hipStream_t stream) {
  MegaP P;
  P.x    = (const float*)d_in[0];
  P.mask = (const float*)d_in[1];
  P.dww  = (const float*)d_in[2];
  P.dwb  = (const float*)d_in[3];
  P.pww  = (const float*)d_in[4];
  P.pwb  = (const float*)d_in[5];
  P.n0g  = (const float*)d_in[6];
  P.n0b  = (const float*)d_in[7];
  P.nsg  = (const float*)d_in[8];
  P.nsb  = (const float*)d_in[9];
  P.neg  = (const float*)d_in[10];
  P.neb  = (const float*)d_in[11];
  P.Wq   = (const float*)d_in[12];
  P.Wk   = (const float*)d_in[13];
  P.Wv   = (const float*)d_in[14];
  P.Wo   = (const float*)d_in[15];
  P.fcw  = (const float*)d_in[16];
  P.fcb  = (const float*)d_in[17];
  P.out  = (float*)d_out;

  float* W = (float*)d_ws;
  const size_t NBCT = (size_t)BB * CC * TT;
  const size_t NBTD = (size_t)BB * TT * DK;
  P.part0 = W;
  P.parts = W + 4096;
  P.pml   = W + 4096 + 5 * 2048;
  P.ob    = (short*)(P.pml + 131072);
  P.sb    = P.ob + NBCT;
  P.qb    = P.sb + NBCT;
  P.kb    = P.qb + NBTD;
  P.vt    = P.kb + NBTD;
  P.pacc  = P.vt + NBTD;
  P.pwwb  = P.pacc + NBTD * NSPLIT;
  P.wqkvb = P.pwwb + 65536;
  P.wo2b  = P.wqkvb + 24576;
  P.fcwb  = P.wo2b + 8192;
  P.barr  = (unsigned*)(P.fcwb + 16384);  // 8 x (counter,flag) = 64 B

  hipMemsetAsync(P.barr, 0, 64, stream);
  k_mega<<<NBLK, 256, 0, stream>>>(P);
}